// Round 6
// baseline (84.294 us; speedup 1.0000x reference)
//
#include <hip/hip_runtime.h>
#include <math.h>

#define HH 1024
#define WW 1024
#define BB 32
#define HW (HH*WW)                 // 1048576 pixels per sample
#define CHUNKS 64                  // blocks per sample (16 rows each)
#define PIXB (HW/CHUNKS)           // 16384 pixels per block
#define THREADS 256
#define ITERS (PIXB/4/THREADS)     // 16 float4 iterations (one row per iter)
#define NBLK (BB*CHUNKS)           // 2048 blocks

typedef float f32x4 __attribute__((ext_vector_type(4)));
typedef int   i32x4 __attribute__((ext_vector_type(4)));

struct WsLayout {
    float cel_part[NBLK];
    int tcnt[NBLK], gcnt[NBLK];
    int trmin[NBLK], trmax[NBLK], tcmin[NBLK], tcmax[NBLK];
    int grmin[NBLK], grmax[NBLK], gcmin[NBLK], gcmax[NBLK];
};

__device__ __forceinline__ float sqf(float v) { return v * v; }

__global__ __launch_bounds__(THREADS) void wnet_main(
        const float* __restrict__ x, const int* __restrict__ gt,
        WsLayout* __restrict__ ws) {
    const int blk   = blockIdx.x;
    const int b     = blk >> 6;
    const int chunk = blk & 63;
    const f32x4* __restrict__ x0 = reinterpret_cast<const f32x4*>(x + (size_t)b * 2 * HW);
    const f32x4* __restrict__ x1 = x0 + (HW/4);
    const i32x4* __restrict__ g  = reinterpret_cast<const i32x4*>(gt + (size_t)b * HW);
    const int base4 = chunk * (PIXB/4);
    const int row0  = chunk * 16;

    float cel = 0.0f;
    int cnt_t = 0, cnt_g = 0;                   // per-lane counts
    unsigned int umask_t = 0u, umask_g = 0u;    // per-lane "ever seen" 4-bit col masks
    unsigned int rmask_t = 0u, rmask_g = 0u;    // per-lane 16-bit row-occupancy masks

    // loop body: loads + pure VALU (no wave ops, no branches, no SALU chains)
    #pragma unroll 4
    for (int it = 0; it < ITERS; ++it) {
        const int idx4 = base4 + it*THREADS + threadIdx.x;
        const f32x4 a  = x0[idx4];              // A/B vs R5: plain loads (no nt)
        const f32x4 c  = x1[idx4];
        const i32x4 gv = g[idx4];
        unsigned int it_t = 0u, it_g = 0u;
        #pragma unroll
        for (int j = 0; j < 4; ++j) {
            const float xa = a[j];
            const float xc = c[j];
            it_t |= (xc > xa)    ? (1u << j) : 0u;
            it_g |= (gv[j] == 1) ? (1u << j) : 0u;
            // cel = softplus(x_other - x_gt), stable form
            const float s = xc - xa;
            cel += fmaxf(s, 0.0f) - ((gv[j] == 1) ? s : 0.0f)
                 + __logf(1.0f + __expf(-fabsf(s)));
        }
        cnt_t += __builtin_popcount(it_t);
        cnt_g += __builtin_popcount(it_g);
        umask_t |= it_t;  umask_g |= it_g;
        rmask_t |= (it_t ? 1u : 0u) << it;      // row = row0 + it
        rmask_g |= (it_g ? 1u : 0u) << it;
    }

    // ---- epilogue: lane reductions ----
    unsigned int cnts = (unsigned int)cnt_t | ((unsigned int)cnt_g << 16); // <=64 each
    unsigned int rmsk = rmask_t | (rmask_g << 16);
    #pragma unroll
    for (int o = 32; o > 0; o >>= 1) {
        cel  += __shfl_down(cel, o);
        cnts += __shfl_down(cnts, o);           // sums <= 4096 per half: no carry
        rmsk |= __shfl_down(rmsk, o);
    }
    const unsigned int rT = rmsk & 0xFFFFu, rG = rmsk >> 16;
    int rmin_t = HH, rmax_t = -1, rmin_g = HH, rmax_g = -1;
    if (rT) { rmin_t = row0 + __builtin_ctz(rT); rmax_t = row0 + 31 - __builtin_clz(rT); }
    if (rG) { rmin_g = row0 + __builtin_ctz(rG); rmax_g = row0 + 31 - __builtin_clz(rG); }

    // ---- column bbox: 8 ballots total ----
    // column of (lane, j) = wcb + 4*lane + j (constant across iterations)
    const int wcb = (threadIdx.x & ~63) << 2;
    int cmin_t = WW, cmax_t = -1, cmin_g = WW, cmax_g = -1;
    #pragma unroll
    for (int j = 0; j < 4; ++j) {
        const unsigned long long bt = __ballot((umask_t >> j) & 1u);
        const unsigned long long bg = __ballot((umask_g >> j) & 1u);
        if (bt) {
            cmin_t = min(cmin_t, wcb + (__builtin_ctzll(bt) << 2) + j);
            cmax_t = max(cmax_t, wcb + ((63 - __builtin_clzll(bt)) << 2) + j);
        }
        if (bg) {
            cmin_g = min(cmin_g, wcb + (__builtin_ctzll(bg) << 2) + j);
            cmax_g = max(cmax_g, wcb + ((63 - __builtin_clzll(bg)) << 2) + j);
        }
    }

    // ---- cross-wave reduce via LDS, one writer per block ----
    __shared__ float s_cel[4];
    __shared__ int   s_v[4][10];
    const int wid  = threadIdx.x >> 6;
    const int lane = threadIdx.x & 63;
    if (lane == 0) {
        s_cel[wid]  = cel;
        s_v[wid][0] = (int)(cnts & 0xFFFFu);  s_v[wid][1] = (int)(cnts >> 16);
        s_v[wid][2] = rmin_t; s_v[wid][3] = rmax_t;
        s_v[wid][4] = cmin_t; s_v[wid][5] = cmax_t;
        s_v[wid][6] = rmin_g; s_v[wid][7] = rmax_g;
        s_v[wid][8] = cmin_g; s_v[wid][9] = cmax_g;
    }
    __syncthreads();
    if (threadIdx.x == 0) {
        ws->cel_part[blk] = s_cel[0] + s_cel[1] + s_cel[2] + s_cel[3];
        ws->tcnt[blk]  = s_v[0][0] + s_v[1][0] + s_v[2][0] + s_v[3][0];
        ws->gcnt[blk]  = s_v[0][1] + s_v[1][1] + s_v[2][1] + s_v[3][1];
        ws->trmin[blk] = min(min(s_v[0][2], s_v[1][2]), min(s_v[2][2], s_v[3][2]));
        ws->trmax[blk] = max(max(s_v[0][3], s_v[1][3]), max(s_v[2][3], s_v[3][3]));
        ws->tcmin[blk] = min(min(s_v[0][4], s_v[1][4]), min(s_v[2][4], s_v[3][4]));
        ws->tcmax[blk] = max(max(s_v[0][5], s_v[1][5]), max(s_v[2][5], s_v[3][5]));
        ws->grmin[blk] = min(min(s_v[0][6], s_v[1][6]), min(s_v[2][6], s_v[3][6]));
        ws->grmax[blk] = max(max(s_v[0][7], s_v[1][7]), max(s_v[2][7], s_v[3][7]));
        ws->gcmin[blk] = min(min(s_v[0][8], s_v[1][8]), min(s_v[2][8], s_v[3][8]));
        ws->gcmax[blk] = max(max(s_v[0][9], s_v[1][9]), max(s_v[2][9], s_v[3][9]));
    }
}

__global__ __launch_bounds__(256) void wnet_finalize(
        const WsLayout* __restrict__ ws, float* __restrict__ out) {
    __shared__ float s_cel[4];
    __shared__ float s_dc[BB], s_dl[BB];
    __shared__ int   s_tc[BB], s_gc[BB], s_fl[BB];

    float c = 0.0f;
    for (int i = threadIdx.x; i < NBLK; i += 256) c += ws->cel_part[i];
    #pragma unroll
    for (int o = 32; o > 0; o >>= 1) c += __shfl_down(c, o);
    const int wid  = threadIdx.x >> 6;
    const int lane = threadIdx.x & 63;
    if (lane == 0) s_cel[wid] = c;

    const int b    = threadIdx.x >> 3;   // 0..31
    const int part = threadIdx.x & 7;    // 0..7
    int tcs = 0, gcs = 0;
    int a1 = HH, a2 = -1, a3 = WW, a4 = -1;
    int a5 = HH, a6 = -1, a7 = WW, a8 = -1;
    #pragma unroll
    for (int k = 0; k < 8; ++k) {
        const int idx = b*64 + part*8 + k;
        tcs += ws->tcnt[idx];  gcs += ws->gcnt[idx];
        a1 = min(a1, ws->trmin[idx]);  a2 = max(a2, ws->trmax[idx]);
        a3 = min(a3, ws->tcmin[idx]);  a4 = max(a4, ws->tcmax[idx]);
        a5 = min(a5, ws->grmin[idx]);  a6 = max(a6, ws->grmax[idx]);
        a7 = min(a7, ws->gcmin[idx]);  a8 = max(a8, ws->gcmax[idx]);
    }
    #pragma unroll
    for (int o = 4; o > 0; o >>= 1) {
        tcs += __shfl_down(tcs, o, 8);  gcs += __shfl_down(gcs, o, 8);
        a1 = min(a1, __shfl_down(a1, o, 8));  a2 = max(a2, __shfl_down(a2, o, 8));
        a3 = min(a3, __shfl_down(a3, o, 8));  a4 = max(a4, __shfl_down(a4, o, 8));
        a5 = min(a5, __shfl_down(a5, o, 8));  a6 = max(a6, __shfl_down(a6, o, 8));
        a7 = min(a7, __shfl_down(a7, o, 8));  a8 = max(a8, __shfl_down(a8, o, 8));
    }
    if (part == 0) {
        const float xrmin = (float)a1, xrmax = (float)a2;
        const float xcmin = (float)a3, xcmax = (float)a4;
        const float yrmin = (float)a5, yrmax = (float)a6;
        const float ycmin = (float)a7, ycmax = (float)a8;
        // faithful to reference: row coords / W, col coords / H
        const float xcx  = (xrmin + xrmax) * 0.5f / (float)WW;
        const float xcy  = (xcmin + xcmax) * 0.5f / (float)HH;
        const float xlen = sqf((xrmax - xrmin) / (float)WW) + sqf((xcmax - xcmin) / (float)HH);
        const float gcx  = (yrmin + yrmax) * 0.5f / (float)WW;
        const float gcy  = (ycmin + ycmax) * 0.5f / (float)HH;
        const float glen = sqf((yrmax - yrmin) / (float)WW) + sqf((ycmax - ycmin) / (float)HH);
        s_dc[b] = sqf(xcx - gcx) + sqf(xcy - gcy);
        s_dl[b] = sqf(xlen - glen);
        s_tc[b] = tcs;  s_gc[b] = gcs;
        s_fl[b] = (tcs > 0 && gcs > 0) ? 1 : 0;
    }
    __syncthreads();
    if (threadIdx.x == 0) {
        const float celT = s_cel[0] + s_cel[1] + s_cel[2] + s_cel[3];
        int tcT = 0, gcT = 0, fl = 1;
        float dc = 0.0f, dl = 0.0f;
        for (int i = 0; i < BB; ++i) {
            tcT += s_tc[i];  gcT += s_gc[i];
            fl  &= s_fl[i];
            dc  += s_dc[i];  dl += s_dl[i];
        }
        const float area = (float)HW * (float)BB;       // 33554432
        const float cel_loss = celT / area;
        const float al = ((float)tcT - (float)gcT) / area;
        out[0] = cel_loss + al * al
               + 0.5f * (float)fl * (dc / (float)BB + dl / (float)BB);
    }
}

extern "C" void kernel_launch(void* const* d_in, const int* in_sizes, int n_in,
                              void* d_out, int out_size, void* d_ws, size_t ws_size,
                              hipStream_t stream) {
    const float* x  = (const float*)d_in[0];
    const int*   gt = (const int*)d_in[1];
    float* out = (float*)d_out;
    WsLayout* ws = (WsLayout*)d_ws;

    hipLaunchKernelGGL(wnet_main, dim3(NBLK), dim3(THREADS), 0, stream, x, gt, ws);
    hipLaunchKernelGGL(wnet_finalize, dim3(1), dim3(256), 0, stream, ws, out);
}

// Round 7
// 73.315 us; speedup vs baseline: 1.1498x; 1.1498x over previous
//
#include <hip/hip_runtime.h>
#include <math.h>

#define HH 1024
#define WW 1024
#define BB 32
#define HW (HH*WW)                 // 1048576 pixels per sample
#define CHUNKS 64                  // blocks per sample (16 rows each)
#define PIXB (HW/CHUNKS)           // 16384 pixels per block
#define THREADS 256
#define ITERS (PIXB/4/THREADS)     // 16 float4 iterations (one row per iter)
#define NBLK (BB*CHUNKS)           // 2048 blocks

typedef float f32x4 __attribute__((ext_vector_type(4)));
typedef int   i32x4 __attribute__((ext_vector_type(4)));

struct WsLayout {
    float cel_part[NBLK];
    int tcnt[NBLK], gcnt[NBLK];
    int trmin[NBLK], trmax[NBLK], tcmin[NBLK], tcmax[NBLK];
    int grmin[NBLK], grmax[NBLK], gcmin[NBLK], gcmax[NBLK];
};

__device__ __forceinline__ float sqf(float v) { return v * v; }

__global__ __launch_bounds__(THREADS) void wnet_main(
        const float* __restrict__ x, const int* __restrict__ gt,
        WsLayout* __restrict__ ws) {
    const int blk   = blockIdx.x;
    const int b     = blk >> 6;
    const int chunk = blk & 63;
    const f32x4* __restrict__ x0 = reinterpret_cast<const f32x4*>(x + (size_t)b * 2 * HW);
    const f32x4* __restrict__ x1 = x0 + (HW/4);
    const i32x4* __restrict__ g  = reinterpret_cast<const i32x4*>(gt + (size_t)b * HW);
    const int base4 = chunk * (PIXB/4);
    const int row0  = chunk * 16;

    float cel = 0.0f;
    int cnt_t = 0, cnt_g = 0;                   // per-lane counts
    unsigned int umask_t = 0u, umask_g = 0u;    // per-lane "ever seen" 4-bit col masks
    unsigned int rmask_t = 0u, rmask_g = 0u;    // per-lane 16-bit row-occupancy masks

    // depth-2 software pipeline: issue next iteration's loads before
    // processing current data (doubles loads-in-flight, +12 VGPR).
    int idx = base4 + threadIdx.x;
    f32x4 a_c = __builtin_nontemporal_load(&x0[idx]);
    f32x4 c_c = __builtin_nontemporal_load(&x1[idx]);
    i32x4 g_c = __builtin_nontemporal_load(&g[idx]);

    #pragma unroll 4
    for (int it = 0; it < ITERS; ++it) {
        const int nit = (it + 1 < ITERS) ? it + 1 : it;   // uniform, branchless
        const int nidx = base4 + nit*THREADS + threadIdx.x;
        const f32x4 a_n = __builtin_nontemporal_load(&x0[nidx]);
        const f32x4 c_n = __builtin_nontemporal_load(&x1[nidx]);
        const i32x4 g_n = __builtin_nontemporal_load(&g[nidx]);

        unsigned int it_t = 0u, it_g = 0u;
        #pragma unroll
        for (int j = 0; j < 4; ++j) {
            const float xa = a_c[j];
            const float xc = c_c[j];
            it_t |= (xc > xa)     ? (1u << j) : 0u;
            it_g |= (g_c[j] == 1) ? (1u << j) : 0u;
            // cel = softplus(x_other - x_gt), stable form
            const float s = xc - xa;
            cel += fmaxf(s, 0.0f) - ((g_c[j] == 1) ? s : 0.0f)
                 + __logf(1.0f + __expf(-fabsf(s)));
        }
        cnt_t += __builtin_popcount(it_t);
        cnt_g += __builtin_popcount(it_g);
        umask_t |= it_t;  umask_g |= it_g;
        rmask_t |= (it_t ? 1u : 0u) << it;      // row = row0 + it
        rmask_g |= (it_g ? 1u : 0u) << it;

        a_c = a_n;  c_c = c_n;  g_c = g_n;
    }

    // ---- epilogue: lane reductions ----
    unsigned int cnts = (unsigned int)cnt_t | ((unsigned int)cnt_g << 16); // <=64 each
    unsigned int rmsk = rmask_t | (rmask_g << 16);
    #pragma unroll
    for (int o = 32; o > 0; o >>= 1) {
        cel  += __shfl_down(cel, o);
        cnts += __shfl_down(cnts, o);           // sums <= 4096 per half: no carry
        rmsk |= __shfl_down(rmsk, o);
    }
    const unsigned int rT = rmsk & 0xFFFFu, rG = rmsk >> 16;
    int rmin_t = HH, rmax_t = -1, rmin_g = HH, rmax_g = -1;
    if (rT) { rmin_t = row0 + __builtin_ctz(rT); rmax_t = row0 + 31 - __builtin_clz(rT); }
    if (rG) { rmin_g = row0 + __builtin_ctz(rG); rmax_g = row0 + 31 - __builtin_clz(rG); }

    // ---- column bbox: 8 ballots total ----
    // column of (lane, j) = wcb + 4*lane + j (constant across iterations)
    const int wcb = (threadIdx.x & ~63) << 2;
    int cmin_t = WW, cmax_t = -1, cmin_g = WW, cmax_g = -1;
    #pragma unroll
    for (int j = 0; j < 4; ++j) {
        const unsigned long long bt = __ballot((umask_t >> j) & 1u);
        const unsigned long long bg = __ballot((umask_g >> j) & 1u);
        if (bt) {
            cmin_t = min(cmin_t, wcb + (__builtin_ctzll(bt) << 2) + j);
            cmax_t = max(cmax_t, wcb + ((63 - __builtin_clzll(bt)) << 2) + j);
        }
        if (bg) {
            cmin_g = min(cmin_g, wcb + (__builtin_ctzll(bg) << 2) + j);
            cmax_g = max(cmax_g, wcb + ((63 - __builtin_clzll(bg)) << 2) + j);
        }
    }

    // ---- cross-wave reduce via LDS, one writer per block ----
    __shared__ float s_cel[4];
    __shared__ int   s_v[4][10];
    const int wid  = threadIdx.x >> 6;
    const int lane = threadIdx.x & 63;
    if (lane == 0) {
        s_cel[wid]  = cel;
        s_v[wid][0] = (int)(cnts & 0xFFFFu);  s_v[wid][1] = (int)(cnts >> 16);
        s_v[wid][2] = rmin_t; s_v[wid][3] = rmax_t;
        s_v[wid][4] = cmin_t; s_v[wid][5] = cmax_t;
        s_v[wid][6] = rmin_g; s_v[wid][7] = rmax_g;
        s_v[wid][8] = cmin_g; s_v[wid][9] = cmax_g;
    }
    __syncthreads();
    if (threadIdx.x == 0) {
        ws->cel_part[blk] = s_cel[0] + s_cel[1] + s_cel[2] + s_cel[3];
        ws->tcnt[blk]  = s_v[0][0] + s_v[1][0] + s_v[2][0] + s_v[3][0];
        ws->gcnt[blk]  = s_v[0][1] + s_v[1][1] + s_v[2][1] + s_v[3][1];
        ws->trmin[blk] = min(min(s_v[0][2], s_v[1][2]), min(s_v[2][2], s_v[3][2]));
        ws->trmax[blk] = max(max(s_v[0][3], s_v[1][3]), max(s_v[2][3], s_v[3][3]));
        ws->tcmin[blk] = min(min(s_v[0][4], s_v[1][4]), min(s_v[2][4], s_v[3][4]));
        ws->tcmax[blk] = max(max(s_v[0][5], s_v[1][5]), max(s_v[2][5], s_v[3][5]));
        ws->grmin[blk] = min(min(s_v[0][6], s_v[1][6]), min(s_v[2][6], s_v[3][6]));
        ws->grmax[blk] = max(max(s_v[0][7], s_v[1][7]), max(s_v[2][7], s_v[3][7]));
        ws->gcmin[blk] = min(min(s_v[0][8], s_v[1][8]), min(s_v[2][8], s_v[3][8]));
        ws->gcmax[blk] = max(max(s_v[0][9], s_v[1][9]), max(s_v[2][9], s_v[3][9]));
    }
}

__global__ __launch_bounds__(256) void wnet_finalize(
        const WsLayout* __restrict__ ws, float* __restrict__ out) {
    __shared__ float s_cel[4];
    __shared__ float s_dc[BB], s_dl[BB];
    __shared__ int   s_tc[BB], s_gc[BB], s_fl[BB];

    float c = 0.0f;
    for (int i = threadIdx.x; i < NBLK; i += 256) c += ws->cel_part[i];
    #pragma unroll
    for (int o = 32; o > 0; o >>= 1) c += __shfl_down(c, o);
    const int wid  = threadIdx.x >> 6;
    const int lane = threadIdx.x & 63;
    if (lane == 0) s_cel[wid] = c;

    const int b    = threadIdx.x >> 3;   // 0..31
    const int part = threadIdx.x & 7;    // 0..7
    int tcs = 0, gcs = 0;
    int a1 = HH, a2 = -1, a3 = WW, a4 = -1;
    int a5 = HH, a6 = -1, a7 = WW, a8 = -1;
    #pragma unroll
    for (int k = 0; k < 8; ++k) {
        const int idx = b*64 + part*8 + k;
        tcs += ws->tcnt[idx];  gcs += ws->gcnt[idx];
        a1 = min(a1, ws->trmin[idx]);  a2 = max(a2, ws->trmax[idx]);
        a3 = min(a3, ws->tcmin[idx]);  a4 = max(a4, ws->tcmax[idx]);
        a5 = min(a5, ws->grmin[idx]);  a6 = max(a6, ws->grmax[idx]);
        a7 = min(a7, ws->gcmin[idx]);  a8 = max(a8, ws->gcmax[idx]);
    }
    #pragma unroll
    for (int o = 4; o > 0; o >>= 1) {
        tcs += __shfl_down(tcs, o, 8);  gcs += __shfl_down(gcs, o, 8);
        a1 = min(a1, __shfl_down(a1, o, 8));  a2 = max(a2, __shfl_down(a2, o, 8));
        a3 = min(a3, __shfl_down(a3, o, 8));  a4 = max(a4, __shfl_down(a4, o, 8));
        a5 = min(a5, __shfl_down(a5, o, 8));  a6 = max(a6, __shfl_down(a6, o, 8));
        a7 = min(a7, __shfl_down(a7, o, 8));  a8 = max(a8, __shfl_down(a8, o, 8));
    }
    if (part == 0) {
        const float xrmin = (float)a1, xrmax = (float)a2;
        const float xcmin = (float)a3, xcmax = (float)a4;
        const float yrmin = (float)a5, yrmax = (float)a6;
        const float ycmin = (float)a7, ycmax = (float)a8;
        // faithful to reference: row coords / W, col coords / H
        const float xcx  = (xrmin + xrmax) * 0.5f / (float)WW;
        const float xcy  = (xcmin + xcmax) * 0.5f / (float)HH;
        const float xlen = sqf((xrmax - xrmin) / (float)WW) + sqf((xcmax - xcmin) / (float)HH);
        const float gcx  = (yrmin + yrmax) * 0.5f / (float)WW;
        const float gcy  = (ycmin + ycmax) * 0.5f / (float)HH;
        const float glen = sqf((yrmax - yrmin) / (float)WW) + sqf((ycmax - ycmin) / (float)HH);
        s_dc[b] = sqf(xcx - gcx) + sqf(xcy - gcy);
        s_dl[b] = sqf(xlen - glen);
        s_tc[b] = tcs;  s_gc[b] = gcs;
        s_fl[b] = (tcs > 0 && gcs > 0) ? 1 : 0;
    }
    __syncthreads();
    if (threadIdx.x == 0) {
        const float celT = s_cel[0] + s_cel[1] + s_cel[2] + s_cel[3];
        int tcT = 0, gcT = 0, fl = 1;
        float dc = 0.0f, dl = 0.0f;
        for (int i = 0; i < BB; ++i) {
            tcT += s_tc[i];  gcT += s_gc[i];
            fl  &= s_fl[i];
            dc  += s_dc[i];  dl += s_dl[i];
        }
        const float area = (float)HW * (float)BB;       // 33554432
        const float cel_loss = celT / area;
        const float al = ((float)tcT - (float)gcT) / area;
        out[0] = cel_loss + al * al
               + 0.5f * (float)fl * (dc / (float)BB + dl / (float)BB);
    }
}

extern "C" void kernel_launch(void* const* d_in, const int* in_sizes, int n_in,
                              void* d_out, int out_size, void* d_ws, size_t ws_size,
                              hipStream_t stream) {
    const float* x  = (const float*)d_in[0];
    const int*   gt = (const int*)d_in[1];
    float* out = (float*)d_out;
    WsLayout* ws = (WsLayout*)d_ws;

    hipLaunchKernelGGL(wnet_main, dim3(NBLK), dim3(THREADS), 0, stream, x, gt, ws);
    hipLaunchKernelGGL(wnet_finalize, dim3(1), dim3(256), 0, stream, ws, out);
}